// Round 3
// baseline (3921.892 us; speedup 1.0000x reference)
//
#include <hip/hip_runtime.h>

#define N_TOK 131072
#define D_INP 256
#define D_HID 512
#define D_OUTP 256
#define NEXP 8

typedef unsigned short u16;
using short8  = __attribute__((ext_vector_type(8))) short;
using floatx4 = __attribute__((ext_vector_type(4))) float;

static __device__ __forceinline__ u16 f2bf(float f) {
  unsigned u = __float_as_uint(f);
  u = (u + 0x7fffu + ((u >> 16) & 1u)) >> 16;   // round-to-nearest-even
  return (u16)u;
}
static __device__ __forceinline__ float bf2f(u16 v) {
  return __uint_as_float((unsigned)v << 16);
}
static __device__ __forceinline__ float gelu_exact(float v) {
  return 0.5f * v * (1.0f + erff(v * 0.70710678118654752f));
}
// async global->LDS, 16B per lane; dest must be wave-uniform base + lane*16
static __device__ __forceinline__ void gload16(const void* g, void* l) {
  __builtin_amdgcn_global_load_lds(
      (const __attribute__((address_space(1))) void*)g,
      (__attribute__((address_space(3))) void*)l, 16, 0, 0);
}

// ---------------------------------------------------------------------------
// Gating: one wave per token. logits = tanh(x@gw1) @ gw2 ; softmax ; top-2 ;
// renormalize. Writes (e1,e2) + (w1,w2) per token. Also casts x -> bf16.
// ---------------------------------------------------------------------------
__global__ __launch_bounds__(256) void gate_cast(
    const float* __restrict__ x, const float* __restrict__ gw1,
    const float* __restrict__ gw2, u16* __restrict__ xb,
    int2* __restrict__ tope, float2* __restrict__ wts) {
  const int lane  = threadIdx.x & 63;
  const int token = blockIdx.x * 4 + (threadIdx.x >> 6);

  const float4 v = ((const float4*)(x + (size_t)token * D_INP))[lane];

  ushort4 b4;
  b4.x = f2bf(v.x); b4.y = f2bf(v.y); b4.z = f2bf(v.z); b4.w = f2bf(v.w);
  *(ushort4*)(xb + (size_t)token * D_INP + lane * 4) = b4;

  float p[16];
#pragma unroll
  for (int j = 0; j < 16; ++j) p[j] = 0.f;
  const float va[4] = {v.x, v.y, v.z, v.w};
  const int d0 = lane * 4;
#pragma unroll
  for (int r = 0; r < 4; ++r) {
    const float xr = va[r];
    const float4* g4 = (const float4*)(gw1 + (size_t)(d0 + r) * 16);
    float4 a0 = g4[0], a1 = g4[1], a2 = g4[2], a3 = g4[3];
    p[0]  += xr * a0.x; p[1]  += xr * a0.y; p[2]  += xr * a0.z; p[3]  += xr * a0.w;
    p[4]  += xr * a1.x; p[5]  += xr * a1.y; p[6]  += xr * a1.z; p[7]  += xr * a1.w;
    p[8]  += xr * a2.x; p[9]  += xr * a2.y; p[10] += xr * a2.z; p[11] += xr * a2.w;
    p[12] += xr * a3.x; p[13] += xr * a3.y; p[14] += xr * a3.z; p[15] += xr * a3.w;
  }
#pragma unroll
  for (int m = 1; m < 64; m <<= 1) {
#pragma unroll
    for (int j = 0; j < 16; ++j) p[j] += __shfl_xor(p[j], m, 64);
  }
  float tj[16];
#pragma unroll
  for (int j = 0; j < 16; ++j) tj[j] = tanhf(p[j]);

  float lg[8];
#pragma unroll
  for (int e = 0; e < 8; ++e) {
    float s = 0.f;
#pragma unroll
    for (int j = 0; j < 16; ++j) s += tj[j] * gw2[j * 8 + e];
    lg[e] = s;
  }
  float mx = lg[0];
#pragma unroll
  for (int e = 1; e < 8; ++e) mx = fmaxf(mx, lg[e]);
  float ex[8], se = 0.f;
#pragma unroll
  for (int e = 0; e < 8; ++e) { ex[e] = expf(lg[e] - mx); se += ex[e]; }
  float inv = 1.f / se;
#pragma unroll
  for (int e = 0; e < 8; ++e) ex[e] *= inv;
  int i1 = 0; float v1 = ex[0];
#pragma unroll
  for (int e = 1; e < 8; ++e) if (ex[e] > v1) { v1 = ex[e]; i1 = e; }
  int i2 = -1; float v2 = -1.f;
#pragma unroll
  for (int e = 0; e < 8; ++e) if (e != i1 && ex[e] > v2) { v2 = ex[e]; i2 = e; }
  float rs = 1.f / (v1 + v2 + 1e-12f);

  if (lane == 0) {
    tope[token] = make_int2(i1, i2);
    wts[token]  = make_float2(v1 * rs, v2 * rs);
  }
}

// ---------------------------------------------------------------------------
// Routing: count per-expert (wave-aggregated), scan (padded to 64), assign.
// ---------------------------------------------------------------------------
__global__ __launch_bounds__(256) void count_k(const int2* __restrict__ tope,
                                               int* __restrict__ counts) {
  int t = blockIdx.x * 256 + threadIdx.x;
  int lane = threadIdx.x & 63;
  int2 ee = tope[t];
#pragma unroll
  for (int e = 0; e < 8; ++e) {
    unsigned long long m1 = __ballot(ee.x == e);
    unsigned long long m2 = __ballot(ee.y == e);
    int c = __popcll(m1) + __popcll(m2);
    if (lane == 0 && c) atomicAdd(counts + e, c);
  }
}

__global__ void scan_k(const int* __restrict__ counts, int* __restrict__ off) {
  if (threadIdx.x == 0 && blockIdx.x == 0) {
    int o = 0;
    for (int e = 0; e < 8; ++e) { off[e] = o; o += (counts[e] + 63) & ~63; }
    off[8] = o;
  }
}

// NOTE: tope and slotOf alias the SAME buffer (each thread reads tope[t]
// before writing slotOf[2t..2t+1]); no __restrict__ here so the compiler
// preserves the load-before-store order.
__global__ __launch_bounds__(256) void assign_k(
    const int2* tope, const float2* __restrict__ wts,
    const int* __restrict__ off, int* __restrict__ cursors,
    int* __restrict__ perm, u16* __restrict__ wgt, int* slotOf) {
  int t = blockIdx.x * 256 + threadIdx.x;
  int lane = threadIdx.x & 63;
  int2 ee = tope[t];
  float2 ww = wts[t];
  unsigned long long lt = (lane == 63) ? 0x7fffffffffffffffULL
                                       : ((1ULL << lane) - 1ULL);
#pragma unroll
  for (int k = 0; k < 2; ++k) {
    int e = k ? ee.y : ee.x;
    float w = k ? ww.y : ww.x;
#pragma unroll
    for (int q = 0; q < 8; ++q) {
      unsigned long long mask = __ballot(e == q);
      if (!mask) continue;
      int leader = __ffsll((long long)mask) - 1;
      int base = 0;
      if (lane == leader) base = atomicAdd(cursors + q, __popcll(mask));
      base = __shfl(base, leader);
      if (e == q) {
        int pos = base + __popcll(mask & lt);
        int slot = off[q] + pos;
        perm[slot] = t;
        wgt[slot] = f2bf(w);
        slotOf[2 * t + k] = slot;
      }
    }
  }
}

// ---------------------------------------------------------------------------
// Weight prep: W[e][k][n] fp32 -> LDS-image bf16 img[e][kt][q][n][8],
// element (k = kt*32 + q*8 + j, n). Staging then = pure linear copy.
// ---------------------------------------------------------------------------
template <int NW>
__global__ __launch_bounds__(256) void wprep(const float* __restrict__ W,
                                             u16* __restrict__ img, int K) {
  const int e = blockIdx.z, kt = blockIdx.x;
  const int chunks = 4 * NW;
  const float* Wp = W + (size_t)e * K * NW;
  u16* ip = img + ((size_t)e * (K / 32) + kt) * (size_t)chunks * 8;
  for (int idx = threadIdx.x; idx < chunks; idx += 256) {
    int q = idx / NW, n = idx % NW;
    int k0 = kt * 32 + q * 8;
    u16 tmp[8];
#pragma unroll
    for (int j = 0; j < 8; ++j) tmp[j] = f2bf(Wp[(size_t)(k0 + j) * NW + n]);
    *(uint4*)(ip + (size_t)idx * 8) = *(uint4*)tmp;
  }
}

// ---------------------------------------------------------------------------
// Fused routed expert: per 64-slot tile, x ->(GEMM1+LN+GELU)-> h1(LDS)
// ->(GEMM2+LN+GELU)-> h2(LDS) ->(GEMM3+bias+w)-> plain stores to y[slot].
// 512 threads = 8 waves. W staging double-buffered into DEAD LDS regions
// (GEMM1: Hs half; GEMM2/3: Axf), one barrier per k-tile.
// ---------------------------------------------------------------------------
__device__ __forceinline__ void ln_gelu_epi(
    floatx4 (&acc)[4][4], const float* __restrict__ bias,
    const float* __restrict__ gam, const float* __restrict__ bet,
    u16* Hs, float* redS, float* redQ, int wv, int cl, int qd) {
#pragma unroll
  for (int c = 0; c < 4; ++c) {
    float bv = bias[wv * 64 + c * 16 + cl];
#pragma unroll
    for (int rt = 0; rt < 4; ++rt)
#pragma unroll
      for (int r = 0; r < 4; ++r) acc[rt][c][r] += bv;
  }
#pragma unroll
  for (int rt = 0; rt < 4; ++rt)
#pragma unroll
    for (int r = 0; r < 4; ++r) {
      float s = 0.f, q2 = 0.f;
#pragma unroll
      for (int c = 0; c < 4; ++c) { float v = acc[rt][c][r]; s += v; q2 += v * v; }
#pragma unroll
      for (int m = 1; m < 16; m <<= 1) {
        s += __shfl_xor(s, m, 64);
        q2 += __shfl_xor(q2, m, 64);
      }
      if (cl == 0) {
        int row = rt * 16 + qd * 4 + r;
        redS[row * 8 + wv] = s;
        redQ[row * 8 + wv] = q2;
      }
    }
  __syncthreads();
  float mean[4][4], rstd[4][4];
#pragma unroll
  for (int rt = 0; rt < 4; ++rt)
#pragma unroll
    for (int r = 0; r < 4; ++r) {
      int row = rt * 16 + qd * 4 + r;
      float s = 0.f, q2 = 0.f;
#pragma unroll
      for (int w = 0; w < 8; ++w) { s += redS[row * 8 + w]; q2 += redQ[row * 8 + w]; }
      float mu = s * (1.f / 512.f);
      float var = q2 * (1.f / 512.f) - mu * mu;
      mean[rt][r] = mu;
      rstd[rt][r] = rsqrtf(var + 1e-5f);
    }
#pragma unroll
  for (int c = 0; c < 4; ++c) {
    int col = wv * 64 + c * 16 + cl;
    float ga = gam[col], be = bet[col];
    int kt2 = col >> 5, q2i = (col >> 3) & 3, j = col & 7;
    u16* dst = Hs + (((kt2 * 4 + q2i) * 64) * 8) + j;
#pragma unroll
    for (int rt = 0; rt < 4; ++rt)
#pragma unroll
      for (int r = 0; r < 4; ++r) {
        int row = rt * 16 + qd * 4 + r;
        float v = (acc[rt][c][r] - mean[rt][r]) * rstd[rt][r] * ga + be;
        dst[row * 8] = f2bf(gelu_exact(v));
      }
  }
}

__global__ __launch_bounds__(512, 1) void moe_fused(
    const u16* __restrict__ xb, const u16* __restrict__ W1i,
    const u16* __restrict__ W2i, const u16* __restrict__ W3i,
    const float* __restrict__ b1, const float* __restrict__ g1,
    const float* __restrict__ be1, const float* __restrict__ b2,
    const float* __restrict__ g2, const float* __restrict__ be2,
    const float* __restrict__ b3, const int* __restrict__ off,
    const int* __restrict__ counts, const int* __restrict__ perm,
    const u16* __restrict__ wgt, u16* __restrict__ y) {
  extern __shared__ __align__(16) char smem[];
  u16*   Axf  = (u16*)smem;                  // [32][64][8]    32 KB
  u16*   Hs   = (u16*)(smem + 32768);        // [16][4][64][8] 64 KB
  u16*   WstA = (u16*)(smem + 98304);        // [4][512][8]    32 KB
  float* redS = (float*)(smem + 131072);     // [64][8]         2 KB
  float* redQ = (float*)(smem + 133120);     //                 2 KB
  int*   sTok = (int*)(smem + 135168);       // [64]
  float* sW   = (float*)(smem + 135424);     // [64]

  const int t = threadIdx.x, lane = t & 63, wv = t >> 6;
  const int cl = lane & 15, qd = lane >> 4;
  const int r0 = blockIdx.x * 64;

  int e = 0;
#pragma unroll
  for (int i = 1; i < 8; ++i) if (r0 >= off[i]) e = i;
  if (r0 >= off[8]) return;
  const int end = off[e] + counts[e];

  if (t < 64) {
    int slot = r0 + t;
    bool v = slot < end;
    sTok[t] = v ? perm[slot] : 0;
    sW[t]   = v ? bf2f(wgt[slot]) : 0.f;
  }
  __syncthreads();

  // gather x rows -> Axf  [c][m][8]; dest = wave-uniform + lane*16
  {
    const int m = t & 63;
    const u16* src = xb + (size_t)sTok[m] * 256;
#pragma unroll
    for (int i = 0; i < 4; ++i) {
      int c = (t >> 6) + i * 8;                 // 0..31
      gload16(src + c * 8, Axf + (size_t)(c * 64 + m) * 8);
    }
  }

  floatx4 acc[4][4];
#pragma unroll
  for (int rt = 0; rt < 4; ++rt)
#pragma unroll
    for (int c = 0; c < 4; ++c) acc[rt][c] = (floatx4){0.f, 0.f, 0.f, 0.f};

  // ---- GEMM1: K=256 (8 k-tiles), dbuf = {WstA, Hs_lo} ----
  {
    const u16* wsrc = W1i + ((size_t)(e * 8)) * 2048 * 8;
#pragma unroll
    for (int i = 0; i < 4; ++i) {
      int idx = t + i * 512;
      gload16(wsrc + (size_t)idx * 8, WstA + (size_t)idx * 8);
    }
    __syncthreads();   // gather + stage0 done
    for (int kt = 0; kt < 8; ++kt) {
      u16* cur = (kt & 1) ? Hs : WstA;
      u16* nxt = (kt & 1) ? WstA : Hs;
      if (kt < 7) {
        const u16* s2 = wsrc + (size_t)(kt + 1) * 2048 * 8;
#pragma unroll
        for (int i = 0; i < 4; ++i) {
          int idx = t + i * 512;
          gload16(s2 + (size_t)idx * 8, nxt + (size_t)idx * 8);
        }
      }
      short8 a[4];
#pragma unroll
      for (int rt = 0; rt < 4; ++rt)
        a[rt] = *(const short8*)(Axf + ((size_t)(kt * 4 + qd) * 64 + rt * 16 + cl) * 8);
#pragma unroll
      for (int c = 0; c < 4; ++c) {
        short8 b = *(const short8*)(cur + ((size_t)qd * 512 + wv * 64 + c * 16 + cl) * 8);
#pragma unroll
        for (int rt = 0; rt < 4; ++rt)
          acc[rt][c] = __builtin_amdgcn_mfma_f32_16x16x32_bf16(a[rt], b, acc[rt][c], 0, 0, 0);
      }
      __syncthreads();
    }
  }
  ln_gelu_epi(acc, b1 + e * D_HID, g1 + e * D_HID, be1 + e * D_HID,
              Hs, redS, redQ, wv, cl, qd);

#pragma unroll
  for (int rt = 0; rt < 4; ++rt)
#pragma unroll
    for (int c = 0; c < 4; ++c) acc[rt][c] = (floatx4){0.f, 0.f, 0.f, 0.f};

  // ---- GEMM2: K=512 (16 k-tiles), A = h1 (LDS), dbuf = {WstA, Axf} ----
  {
    const u16* wsrc = W2i + ((size_t)(e * 16)) * 2048 * 8;
#pragma unroll
    for (int i = 0; i < 4; ++i) {
      int idx = t + i * 512;
      gload16(wsrc + (size_t)idx * 8, WstA + (size_t)idx * 8);
    }
    __syncthreads();   // h1 visible + stage0 done
    for (int kt = 0; kt < 16; ++kt) {
      u16* cur = (kt & 1) ? Axf : WstA;
      u16* nxt = (kt & 1) ? WstA : Axf;
      if (kt < 15) {
        const u16* s2 = wsrc + (size_t)(kt + 1) * 2048 * 8;
#pragma unroll
        for (int i = 0; i < 4; ++i) {
          int idx = t + i * 512;
          gload16(s2 + (size_t)idx * 8, nxt + (size_t)idx * 8);
        }
      }
      short8 a[4];
#pragma unroll
      for (int rt = 0; rt < 4; ++rt)
        a[rt] = *(const short8*)(Hs + ((size_t)(kt * 4 + qd) * 64 + rt * 16 + cl) * 8);
#pragma unroll
      for (int c = 0; c < 4; ++c) {
        short8 b = *(const short8*)(cur + ((size_t)qd * 512 + wv * 64 + c * 16 + cl) * 8);
#pragma unroll
        for (int rt = 0; rt < 4; ++rt)
          acc[rt][c] = __builtin_amdgcn_mfma_f32_16x16x32_bf16(a[rt], b, acc[rt][c], 0, 0, 0);
      }
      __syncthreads();
    }
  }
  ln_gelu_epi(acc, b2 + e * D_HID, g2 + e * D_HID, be2 + e * D_HID,
              Hs, redS, redQ, wv, cl, qd);

  // ---- GEMM3: K=512, N=256; wave = 64 rows x 32 cols, dbuf = {WstA, Axf} ----
  floatx4 acc3[4][2];
#pragma unroll
  for (int rt = 0; rt < 4; ++rt)
#pragma unroll
    for (int c = 0; c < 2; ++c) acc3[rt][c] = (floatx4){0.f, 0.f, 0.f, 0.f};

  {
    const u16* wsrc = W3i + ((size_t)(e * 16)) * 1024 * 8;
#pragma unroll
    for (int i = 0; i < 2; ++i) {
      int idx = t + i * 512;
      gload16(wsrc + (size_t)idx * 8, WstA + (size_t)idx * 8);
    }
    __syncthreads();   // h2 visible + stage0 done
    for (int kt = 0; kt < 16; ++kt) {
      u16* cur = (kt & 1) ? Axf : WstA;
      u16* nxt = (kt & 1) ? WstA : Axf;
      if (kt < 15) {
        const u16* s2 = wsrc + (size_t)(kt + 1) * 1024 * 8;
#pragma unroll
        for (int i = 0; i < 2; ++i) {
          int idx = t + i * 512;
          gload16(s2 + (size_t)idx * 8, nxt + (size_t)idx * 8);
        }
      }
      short8 a[4];
#pragma unroll
      for (int rt = 0; rt < 4; ++rt)
        a[rt] = *(const short8*)(Hs + ((size_t)(kt * 4 + qd) * 64 + rt * 16 + cl) * 8);
#pragma unroll
      for (int c = 0; c < 2; ++c) {
        short8 b = *(const short8*)(cur + ((size_t)qd * 256 + wv * 32 + c * 16 + cl) * 8);
#pragma unroll
        for (int rt = 0; rt < 4; ++rt)
          acc3[rt][c] = __builtin_amdgcn_mfma_f32_16x16x32_bf16(a[rt], b, acc3[rt][c], 0, 0, 0);
      }
      __syncthreads();
    }
  }

  // epilogue 3: y[slot] = bf16( w * (acc + b3) )  — plain stores, no atomics
  float b3v[2];
#pragma unroll
  for (int c = 0; c < 2; ++c) b3v[c] = b3[e * D_OUTP + wv * 32 + c * 16 + cl];
#pragma unroll
  for (int rt = 0; rt < 4; ++rt)
#pragma unroll
    for (int r = 0; r < 4; ++r) {
      int sR = rt * 16 + qd * 4 + r;
      float w = sW[sR];
      u16* ybase = y + (size_t)(r0 + sR) * 256;
#pragma unroll
      for (int c = 0; c < 2; ++c) {
        int col = wv * 32 + c * 16 + cl;
        ybase[col] = f2bf(w * (acc3[rt][c][r] + b3v[c]));
      }
    }
}

// ---------------------------------------------------------------------------
// Combine: out[t] = y[slotOf[2t]] + y[slotOf[2t+1]]  (weights pre-folded)
// ---------------------------------------------------------------------------
__global__ __launch_bounds__(256) void combine_k(
    const u16* __restrict__ y, const int* __restrict__ slotOf,
    float* __restrict__ out) {
  const int lane  = threadIdx.x & 63;
  const int token = blockIdx.x * 4 + (threadIdx.x >> 6);
  int s1 = slotOf[2 * token], s2 = slotOf[2 * token + 1];
  ushort4 a = ((const ushort4*)(y + (size_t)s1 * 256))[lane];
  ushort4 b = ((const ushort4*)(y + (size_t)s2 * 256))[lane];
  float4 o;
  o.x = bf2f(a.x) + bf2f(b.x);
  o.y = bf2f(a.y) + bf2f(b.y);
  o.z = bf2f(a.z) + bf2f(b.z);
  o.w = bf2f(a.w) + bf2f(b.w);
  ((float4*)(out + (size_t)token * 256))[lane] = o;
}

// ---------------------------------------------------------------------------
// Launcher. ws layout (bytes), total 213,650,560 (<= proven 214 MB budget):
//   xb     @ 0          : 67,108,864
//   y      @ 67108864   : 134,479,872  (262656 slots x 256 bf16)
//   W1i    @ 201588736  : 2,097,152
//   W2i    @ 203685888  : 4,194,304
//   W3i    @ 207880192  : 2,097,152
//   tope   @ 209977344  : 1,048,576   (reused as slotOf by assign_k)
//   wts    @ 211025920  : 1,048,576
//   perm   @ 212074496  : 1,050,624
//   wgt    @ 213125120  : 525,312     (bf16)
//   meta   @ 213650432  : 128
// ---------------------------------------------------------------------------
extern "C" void kernel_launch(void* const* d_in, const int* in_sizes, int n_in,
                              void* d_out, int out_size, void* d_ws,
                              size_t ws_size, hipStream_t stream) {
  const float* x   = (const float*)d_in[0];
  const float* gw1 = (const float*)d_in[1];
  const float* gw2 = (const float*)d_in[2];
  const float* W1  = (const float*)d_in[3];
  const float* b1  = (const float*)d_in[4];
  const float* g1  = (const float*)d_in[5];
  const float* be1 = (const float*)d_in[6];
  const float* W2  = (const float*)d_in[7];
  const float* b2  = (const float*)d_in[8];
  const float* g2  = (const float*)d_in[9];
  const float* be2 = (const float*)d_in[10];
  const float* W3  = (const float*)d_in[11];
  const float* b3  = (const float*)d_in[12];
  float* out = (float*)d_out;

  char* ws = (char*)d_ws;
  u16*    xb   = (u16*)(ws);
  u16*    y    = (u16*)(ws + 67108864);
  u16*    W1i  = (u16*)(ws + 201588736);
  u16*    W2i  = (u16*)(ws + 203685888);
  u16*    W3i  = (u16*)(ws + 207880192);
  int2*   tope = (int2*)(ws + 209977344);
  int*    slotOf = (int*)(ws + 209977344);   // aliases tope (see assign_k)
  float2* wtsp = (float2*)(ws + 211025920);
  int*    perm = (int*)(ws + 212074496);
  u16*    wgt  = (u16*)(ws + 213125120);
  int*    meta = (int*)(ws + 213650432);
  int* counts  = meta;        // 8
  int* cursors = meta + 8;    // 8
  int* off     = meta + 16;   // 9

  static const int LDS_BYTES = 135680;
  hipFuncSetAttribute((const void*)moe_fused,
                      hipFuncAttributeMaxDynamicSharedMemorySize, LDS_BYTES);

  hipMemsetAsync(meta, 0, 64, stream);

  gate_cast<<<N_TOK / 4, 256, 0, stream>>>(x, gw1, gw2, xb, tope, wtsp);
  count_k<<<N_TOK / 256, 256, 0, stream>>>(tope, counts);
  scan_k<<<1, 64, 0, stream>>>(counts, off);
  assign_k<<<N_TOK / 256, 256, 0, stream>>>(tope, wtsp, off, cursors, perm,
                                            wgt, slotOf);

  wprep<512><<<dim3(8, 1, 8), 256, 0, stream>>>(W1, W1i, 256);
  wprep<512><<<dim3(16, 1, 8), 256, 0, stream>>>(W2, W2i, 512);
  wprep<256><<<dim3(16, 1, 8), 256, 0, stream>>>(W3, W3i, 512);

  const int nblk = (2 * N_TOK + NEXP * 63 + 63) / 64;   // 4104
  moe_fused<<<nblk, 512, LDS_BYTES, stream>>>(
      xb, W1i, W2i, W3i, b1, g1, be1, b2, g2, be2, b3,
      off, counts, perm, wgt, y);

  combine_k<<<N_TOK / 4, 256, 0, stream>>>(y, slotOf, out);
}